// Round 8
// baseline (153.808 us; speedup 1.0000x reference)
//
#include <hip/hip_runtime.h>

#define HW   4096
#define HIMG 64
#define CC   256
#define CR   32
#define B_   8
#define XSP  264   // xs pitch (bf16 elems): 264*2=528 B = 33*16 -> b128-aligned, 4-way max

typedef __attribute__((ext_vector_type(8))) short bf16x8;
typedef __attribute__((ext_vector_type(4))) float f32x4;

__device__ inline unsigned short f2bf(float f) {
    union { float f; unsigned u; } v; v.f = f;
    return (unsigned short)((v.u + 0x8000u) >> 16);
}
__device__ inline float bf2f(unsigned short h) {
    union { unsigned u; float f; } v; v.u = ((unsigned)h) << 16; return v.f;
}
__device__ inline unsigned pack2(float a, float b) {
    return (unsigned)f2bf(a) | ((unsigned)f2bf(b) << 16);
}

// ---------------------------------------------------------------------------
// K1: weights -> bf16, concat [Wq;Wk;Wv] into Wb[320][256]; biases into bb.
// ---------------------------------------------------------------------------
__global__ __launch_bounds__(256) void wconv(
    const float* __restrict__ Wq, const float* __restrict__ bq,
    const float* __restrict__ Wk, const float* __restrict__ bk,
    const float* __restrict__ Wv, const float* __restrict__ bv,
    unsigned short* __restrict__ Wb, float* __restrict__ bb)
{
    const int o = blockIdx.x;   // 0..319
    const float* src; const float* bsrc; int orel;
    if (o < 32)      { src = Wq; bsrc = bq; orel = o;      }
    else if (o < 64) { src = Wk; bsrc = bk; orel = o - 32; }
    else             { src = Wv; bsrc = bv; orel = o - 64; }
    Wb[o * CC + threadIdx.x] = f2bf(src[orel * CC + threadIdx.x]);
    if (threadIdx.x == 0) bb[o] = bsrc[orel];
}

// ---------------------------------------------------------------------------
// K2: MEGA kernel. Block = (h, b) via XCD-swizzled 1D grid of 512.
// Phases: stage 3 bf16 x-rows -> GEMM1 (q,k) -> energies+softmax ->
//         4x { GEMM2 (64-ch v chunk) -> apply+residual -> out }.
// No intermediate global traffic; W read from global (L2-resident 160 KB).
// LDS 159.7 KB -> 1 block/CU, 8 waves.
// ---------------------------------------------------------------------------
__global__ __launch_bounds__(512) void mega(
    const unsigned short* __restrict__ Wb, const float* __restrict__ bb,
    const float* __restrict__ x, const float* __restrict__ gamma,
    float* __restrict__ out)
{
    __shared__ unsigned short xs[3 * 64 * XSP];          // 101,376 B [r][px][c]
    __shared__ union U {
        unsigned short xt16[256 * 72];                   // 36,864 B [c][px]
        struct { float qs[64][36]; float ks[3][64][36]; float es[64][9]; } p2; // 39,168 B
        float vs[3 * 64 * 72];                           // 55,296 B [r][ch][4|64|4]
    } u;
    __shared__ float aws[64][12];                        //  3,072 B

    // XCD-aware swizzle: XCD (bid&7) owns h-range [xcd*8, xcd*8+8) for all b
    // -> h-halo rows shared within one XCD's L2.
    const int bid = blockIdx.x;
    const int xcd = bid & 7, mm = bid >> 3;
    const int h = xcd * 8 + (mm & 7), b = mm >> 3;
    const int t = threadIdx.x;
    const int lane = t & 63, wv = t >> 6;        // 8 waves
    const int m16 = lane & 15, quad = lane >> 4;

    // ---- P1: stage x rows h-1..h+1 -> xs bf16 [r][px][c] (transposed) ----
    for (int r = 0; r < 3; ++r) {
        const int hh = h + r - 1;
        const bool in = (hh >= 0) && (hh < HIMG);
        if (in) {
            #pragma unroll
            for (int i = 0; i < 8; ++i) {
                int idx = t + 512 * i;                 // 0..4095
                int c = idx >> 4, px4 = (idx & 15) * 4;
                float4 vx = *(const float4*)&x[((size_t)b * CC + c) * HW + hh * 64 + px4];
                uint2 p; p.x = pack2(vx.x, vx.y); p.y = pack2(vx.z, vx.w);
                *(uint2*)&u.xt16[c * 72 + px4] = p;
            }
        }
        __syncthreads();
        if (in) {
            const int px = t & 63, cg = t >> 6;        // wave-uniform cg
            #pragma unroll
            for (int cc = 0; cc < 4; ++cc) {
                int c0 = cg * 32 + cc * 8;
                unsigned short s[8];
                #pragma unroll
                for (int j = 0; j < 8; ++j) s[j] = u.xt16[(c0 + j) * 72 + px];
                uint4 wq;
                wq.x = s[0] | ((unsigned)s[1] << 16);
                wq.y = s[2] | ((unsigned)s[3] << 16);
                wq.z = s[4] | ((unsigned)s[5] << 16);
                wq.w = s[6] | ((unsigned)s[7] << 16);
                *(uint4*)&xs[(r * 64 + px) * XSP + c0] = wq;
            }
        }
        __syncthreads();
    }

    // ---- P2: GEMM1: q (center row) + k (3 rows), 32 ch each ----
    {
        const int tau0 = wv * 4;          // wave -> 4 tiles: same (r, row-block)
        int r, wrow0;
        if (tau0 < 24) { r = tau0 / 8; wrow0 = 32 + ((tau0 % 8) / 4) * 16; }
        else           { r = 1;        wrow0 = ((tau0 - 24) / 4) * 16;     }
        f32x4 acc[4];
        #pragma unroll
        for (int n = 0; n < 4; ++n) acc[n] = (f32x4){0.f, 0.f, 0.f, 0.f};
        for (int ks = 0; ks < 8; ++ks) {
            bf16x8 af = *(const bf16x8*)&Wb[(wrow0 + m16) * CC + ks * 32 + quad * 8];
            #pragma unroll
            for (int n = 0; n < 4; ++n) {
                bf16x8 bf = *(const bf16x8*)&xs[(r * 64 + n * 16 + m16) * XSP + ks * 32 + quad * 8];
                acc[n] = __builtin_amdgcn_mfma_f32_16x16x32_bf16(af, bf, acc[n], 0, 0, 0);
            }
        }
        #pragma unroll
        for (int n = 0; n < 4; ++n) {
            const int px = n * 16 + m16;
            #pragma unroll
            for (int rg = 0; rg < 4; ++rg) {
                float val = acc[n][rg] + bb[wrow0 + quad * 4 + rg];
                if (tau0 < 24) u.p2.ks[r][px][(wrow0 - 32) + quad * 4 + rg] = val;
                else           u.p2.qs[px][wrow0 + quad * 4 + rg] = val;
            }
        }
    }
    __syncthreads();

    // ---- P3: energies + softmax -> aws ----
    for (int id = t; id < 576; id += 512) {
        int px = id / 9, kk = id - px * 9;
        int di = kk / 3, dj = kk - di * 3;
        int hh = h + di - 1, ww = px + dj - 1;
        float e = 0.f;
        if (hh >= 0 && hh < HIMG && ww >= 0 && ww < 64) {
            float sx = 0.f, sy = 0.f, sz = 0.f, sw = 0.f;
            #pragma unroll
            for (int c4 = 0; c4 < 8; ++c4) {
                float4 qv = *(float4*)&u.p2.qs[px][c4 * 4];
                float4 kv = *(float4*)&u.p2.ks[di][ww][c4 * 4];
                sx = fmaf(qv.x, kv.x, sx); sy = fmaf(qv.y, kv.y, sy);
                sz = fmaf(qv.z, kv.z, sz); sw = fmaf(qv.w, kv.w, sw);
            }
            e = (sx + sy) + (sz + sw);
        }
        u.p2.es[px][kk] = e;
    }
    __syncthreads();
    if (t < 64) {
        float m = u.p2.es[t][0];
        #pragma unroll
        for (int kk = 1; kk < 9; ++kk) m = fmaxf(m, u.p2.es[t][kk]);
        float ex[9]; float ssum = 0.f;
        #pragma unroll
        for (int kk = 0; kk < 9; ++kk) { ex[kk] = __expf(u.p2.es[t][kk] - m); ssum += ex[kk]; }
        float inv = 1.f / ssum;
        #pragma unroll
        for (int kk = 0; kk < 9; ++kk) aws[t][kk] = ex[kk] * inv;
    }
    __syncthreads();

    // cache this thread's apply weights (vs entries are 0 for OOB taps)
    const int px0 = (t & 15) * 4;
    float w[4][9];
    #pragma unroll
    for (int i = 0; i < 4; ++i)
        #pragma unroll
        for (int kk = 0; kk < 9; ++kk) w[i][kk] = aws[px0 + i][kk];
    const float g = gamma[0];

    // ---- P4: 4 chunks of 64 v-channels: GEMM2 -> vs -> apply ----
    for (int cb = 0; cb < 4; ++cb) {
        __syncthreads();                       // vs region free
        const int mt = wv >> 1, half = wv & 1; // wave -> 16-ch block, 6 (r,nt) tiles
        const int wrow = 64 + cb * 64 + mt * 16;
        f32x4 acc[6];
        #pragma unroll
        for (int j = 0; j < 6; ++j) acc[j] = (f32x4){0.f, 0.f, 0.f, 0.f};
        for (int ks = 0; ks < 8; ++ks) {
            bf16x8 af = *(const bf16x8*)&Wb[(wrow + m16) * CC + ks * 32 + quad * 8];
            #pragma unroll
            for (int j = 0; j < 6; ++j) {
                int ntp = half * 6 + j;        // 0..11 -> (r, nt)
                int r = ntp >> 2, nt = ntp & 3;
                bf16x8 bf = *(const bf16x8*)&xs[(r * 64 + nt * 16 + m16) * XSP + ks * 32 + quad * 8];
                acc[j] = __builtin_amdgcn_mfma_f32_16x16x32_bf16(af, bf, acc[j], 0, 0, 0);
            }
        }
        #pragma unroll
        for (int j = 0; j < 6; ++j) {
            int ntp = half * 6 + j;
            int r = ntp >> 2, nt = ntp & 3;
            int hh = h + r - 1;
            bool ok = (hh >= 0) && (hh < HIMG);
            #pragma unroll
            for (int rg = 0; rg < 4; ++rg) {
                int ch = mt * 16 + quad * 4 + rg;   // 0..63
                float val = ok ? (acc[j][rg] + bb[wrow + quad * 4 + rg]) : 0.f;
                u.vs[(r * 64 + ch) * 72 + 4 + nt * 16 + m16] = val;
            }
        }
        if (t < 192) {                          // zero px pads
            int r = t / 64, c = t % 64;
            float4 z = make_float4(0.f, 0.f, 0.f, 0.f);
            *(float4*)&u.vs[(r * 64 + c) * 72 + 0]  = z;
            *(float4*)&u.vs[(r * 64 + c) * 72 + 68] = z;
        }
        __syncthreads();
        // apply: thread -> (px0, 2 channels)
        #pragma unroll
        for (int ci = 0; ci < 2; ++ci) {
            int ch = (t >> 4) + 32 * ci;        // 0..63
            int cglob = cb * 64 + ch;
            float a0 = 0.f, a1 = 0.f, a2 = 0.f, a3 = 0.f;
            #pragma unroll
            for (int r = 0; r < 3; ++r) {
                const float* vb = &u.vs[(r * 64 + ch) * 72];
                float4 ctr = *(float4*)&vb[4 + px0];
                float  lft = vb[3 + px0];
                float  rgt = vb[8 + px0];
                int r3 = r * 3;
                a0 = fmaf(w[0][r3], lft,   fmaf(w[0][r3+1], ctr.x, fmaf(w[0][r3+2], ctr.y, a0)));
                a1 = fmaf(w[1][r3], ctr.x, fmaf(w[1][r3+1], ctr.y, fmaf(w[1][r3+2], ctr.z, a1)));
                a2 = fmaf(w[2][r3], ctr.y, fmaf(w[2][r3+1], ctr.z, fmaf(w[2][r3+2], ctr.w, a2)));
                a3 = fmaf(w[3][r3], ctr.z, fmaf(w[3][r3+1], ctr.w, fmaf(w[3][r3+2], rgt,  a3)));
            }
            size_t base = ((size_t)b * CC + cglob) * HW + h * 64 + px0;
            float4 o;
            o.x = fmaf(g, a0, bf2f(xs[(64 + px0 + 0) * XSP + cglob]));
            o.y = fmaf(g, a1, bf2f(xs[(64 + px0 + 1) * XSP + cglob]));
            o.z = fmaf(g, a2, bf2f(xs[(64 + px0 + 2) * XSP + cglob]));
            o.w = fmaf(g, a3, bf2f(xs[(64 + px0 + 3) * XSP + cglob]));
            *(float4*)&out[base] = o;
        }
    }
}

extern "C" void kernel_launch(void* const* d_in, const int* in_sizes, int n_in,
                              void* d_out, int out_size, void* d_ws, size_t ws_size,
                              hipStream_t stream)
{
    const float* x     = (const float*)d_in[0];
    const float* Wq    = (const float*)d_in[1];
    const float* bq    = (const float*)d_in[2];
    const float* Wk    = (const float*)d_in[3];
    const float* bk    = (const float*)d_in[4];
    const float* Wv    = (const float*)d_in[5];
    const float* bv    = (const float*)d_in[6];
    const float* gamma = (const float*)d_in[7];
    float* out = (float*)d_out;

    unsigned short* Wb = (unsigned short*)d_ws;          // 160 KB
    float* bb = (float*)(Wb + 320 * CC);                 // 1.3 KB

    wconv<<<dim3(320), 256, 0, stream>>>(Wq, bq, Wk, bk, Wv, bv, Wb, bb);
    mega<<<dim3(HIMG * B_), 512, 0, stream>>>(Wb, bb, x, gamma, out);
}